// Round 5
// baseline (272.842 us; speedup 1.0000x reference)
//
#include <hip/hip_runtime.h>

typedef __attribute__((ext_vector_type(4)))  float          f32x4;
typedef __attribute__((ext_vector_type(16))) float          f32x16;
typedef __attribute__((ext_vector_type(8)))  short          s16x8;
typedef __attribute__((ext_vector_type(4)))  unsigned short u16x4;
typedef __attribute__((ext_vector_type(8)))  unsigned short u16x8;

#define MFMA_BF16(a, b, c) __builtin_amdgcn_mfma_f32_16x16x32_bf16((a), (b), (c), 0, 0, 0)
#define MFMA32(a, b, c)    __builtin_amdgcn_mfma_f32_32x32x16_bf16((a), (b), (c), 0, 0, 0)

static constexpr int Bb = 2, Ss = 2048, Ee = 1024, Hh = 16, Dd = 64;
static constexpr size_t M4 = 4u * 1024 * 1024; // elems in one activation array
static constexpr size_t M1 = 1024 * 1024;      // elems in one weight matrix

// fp32 -> bf16 round-to-nearest-even
__device__ __forceinline__ unsigned short f2b(float f) {
    unsigned u = __builtin_bit_cast(unsigned, f);
    u += 0x7fffu + ((u >> 16) & 1u);
    return (unsigned short)(u >> 16);
}

// async global->LDS DMA, 16 B per lane
__device__ __forceinline__ void gld_lds16(const unsigned short* g, unsigned short* l) {
    __builtin_amdgcn_global_load_lds(
        (const __attribute__((address_space(1))) unsigned int*)g,
        (__attribute__((address_space(3))) unsigned int*)l, 16, 0, 0);
}

// ---------------------------------------------------------------------------
// Convert fp32 inputs to one contiguous bf16 workspace:
// [query 4M][key_ 4M][value 4M][Wq 1M][Wk 1M][Wv 1M][Wo 1M] = 16M elems.
// ---------------------------------------------------------------------------
struct CvtArgs { const float* src[7]; unsigned short* dst; };

__global__ __launch_bounds__(256) void cvt_bf16(CvtArgs a)
{
    size_t i = ((size_t)blockIdx.x * 256 + threadIdx.x) * 8;
    int seg; size_t off;
    if (i < 3 * M4) { seg = (int)(i / M4);          off = i % M4; }
    else            { size_t j = i - 3 * M4;
                      seg = 3 + (int)(j / M1);      off = j % M1; }
    const float* s = a.src[seg] + off;
    f32x4 x0 = *(const f32x4*)s;
    f32x4 x1 = *(const f32x4*)(s + 4);
    u16x8 o = (u16x8){f2b(x0[0]), f2b(x0[1]), f2b(x0[2]), f2b(x0[3]),
                      f2b(x1[0]), f2b(x1[1]), f2b(x1[2]), f2b(x1[3])};
    *(u16x8*)(a.dst + i) = o;
}

// ---------------------------------------------------------------------------
// m97-style all-bf16 GEMM: C[m][n] = sum_k A[m][k]*W[n][k] + bias[n].
// OUT_MODE: 0 = fp32 [m][n], 1 = bf16 [m][n], 2 = bf16 V-transposed
//           out[(b*1024+n)*2048+s], 3 = bf16 [m][n] scaled by 0.125 (Q path:
//           folds the 1/sqrt(D) attention scale into the projection).
// ---------------------------------------------------------------------------
template <int OUT_MODE>
__device__ __forceinline__ void gemm_bf16_body(const unsigned short* __restrict__ A,
                                               const unsigned short* __restrict__ W,
                                               const float* __restrict__ bias,
                                               void* __restrict__ Cv)
{
    __shared__ __align__(16) unsigned short Al[128 * 32];
    __shared__ __align__(16) unsigned short Bl[128 * 32];

    const int tid  = threadIdx.x;
    const int lane = tid & 63;
    const int wid  = tid >> 6;
    const int quad = lane >> 4;
    const int lr   = lane & 15;
    const int wr   = (wid >> 1) * 64;
    const int wc   = (wid & 1) * 64;
    const int m0   = blockIdx.y * 128;
    const int n0   = blockIdx.x * 128;

    const int srow = wid * 32 + (lane >> 2);
    const int sk8  = (lane & 3) * 8;
    const unsigned short* gA = A + (size_t)(m0 + srow) * 1024 + sk8;
    const unsigned short* gW = W + (size_t)(n0 + srow) * 1024 + sk8;
    unsigned short* lA = &Al[wid * 1024];
    unsigned short* lW = &Bl[wid * 1024];

    f32x4 acc[4][4];
#pragma unroll
    for (int i = 0; i < 4; i++)
#pragma unroll
        for (int j = 0; j < 4; j++) acc[i][j] = (f32x4){0.f, 0.f, 0.f, 0.f};

    for (int ks = 0; ks < 1024; ks += 32) {
        __syncthreads();
        gld_lds16(gA + ks,              lA);
        gld_lds16(gA + ks + 16 * 1024,  lA + 512);
        gld_lds16(gW + ks,              lW);
        gld_lds16(gW + ks + 16 * 1024,  lW + 512);
        __syncthreads();

        s16x8 af[4], bf[4];
#pragma unroll
        for (int t = 0; t < 4; t++) {
            af[t] = *(const s16x8*)&Al[(wr + t * 16 + lr) * 32 + quad * 8];
            bf[t] = *(const s16x8*)&Bl[(wc + t * 16 + lr) * 32 + quad * 8];
        }
#pragma unroll
        for (int mt = 0; mt < 4; mt++)
#pragma unroll
            for (int nt = 0; nt < 4; nt++)
                acc[mt][nt] = MFMA_BF16(af[mt], bf[nt], acc[mt][nt]);
    }

#pragma unroll
    for (int mt = 0; mt < 4; mt++)
#pragma unroll
        for (int nt = 0; nt < 4; nt++) {
            int   col  = n0 + wc + nt * 16 + lr;
            float bcol = bias[col];
            int   rbase = m0 + wr + mt * 16 + quad * 4;
            if (OUT_MODE == 2) {
                int bb = rbase >> 11, s = rbase & 2047;
                u16x4 pk;
#pragma unroll
                for (int r = 0; r < 4; r++) pk[r] = f2b(acc[mt][nt][r] + bcol);
                *(u16x4*)&((unsigned short*)Cv)[((size_t)(bb * 1024 + col)) * 2048 + s] = pk;
            } else {
#pragma unroll
                for (int r = 0; r < 4; r++) {
                    float v = acc[mt][nt][r] + bcol;
                    if (OUT_MODE == 3) v *= 0.125f;
                    if (OUT_MODE == 0)
                        ((float*)Cv)[(size_t)(rbase + r) * 1024 + col] = v;
                    else
                        ((unsigned short*)Cv)[(size_t)(rbase + r) * 1024 + col] = f2b(v);
                }
            }
        }
}

struct GArgs {
    const unsigned short* A[3];
    const unsigned short* W[3];
    const float* bias[3];
    unsigned short* C[3];
};

__global__ __launch_bounds__(256) void proj_gemm(GArgs ga)
{
    int z = blockIdx.z;
    if (z == 2)
        gemm_bf16_body<2>(ga.A[2], ga.W[2], ga.bias[2], ga.C[2]);
    else if (z == 1)
        gemm_bf16_body<1>(ga.A[1], ga.W[1], ga.bias[1], ga.C[1]);
    else
        gemm_bf16_body<3>(ga.A[0], ga.W[0], ga.bias[0], ga.C[0]); // Q, pre-scaled
}

__global__ __launch_bounds__(256) void out_gemm(const unsigned short* __restrict__ A,
                                                const unsigned short* __restrict__ W,
                                                const float* __restrict__ bias,
                                                float* __restrict__ C)
{
    gemm_bf16_body<0>(A, W, bias, C);
}

// ---------------------------------------------------------------------------
// Flash attention v6: 32x32x16 MFMA, S^T operand trick.
//  - block = (b, h, 128 q); 4 waves x 32 q each; 64-key tiles.
//  - S^T = K·Q^T (A = K-frag from LDS, B = Q-frag preloaded from global).
//    C-layout: col = lane&31 = q, row = key = 4*(lane>>5)+8*(reg>>2)+(reg&3)
//    -> reg-quads hold 4 consecutive keys: packed b64 P-writes into [q][k]
//    layout, which is directly the PV A-operand layout.
//  - mask: p = exp(s)·mk·mq + 2^-30. Fully-masked rows (q padded) become
//    exactly-uniform eps -> O = mean(V), matching reference set-semantics.
//    Scale 1/8 pre-folded into Q projection.
//  - row sums accumulate per-lane (fixed q = lane&31); one shfl_xor(32) at end.
// ---------------------------------------------------------------------------
__global__ __launch_bounds__(256)
void flash_attn(const unsigned short* __restrict__ Q,
                const unsigned short* __restrict__ K,
                const unsigned short* __restrict__ Vt,
                const int* __restrict__ mask,
                unsigned short* __restrict__ O)
{
    constexpr int   ST  = 72;                 // row stride: 144 B, 16B-aligned rows
    constexpr float EPS = 9.31322575e-10f;    // 2^-30, exactly representable in bf16
    __shared__ __align__(16) unsigned short Kl[64 * ST];    // [key][d]
    __shared__ __align__(16) unsigned short Vl[64 * ST];    // [d][key] (from Vt)
    __shared__ __align__(16) unsigned short Pl[128 * ST];   // [q][key], per-wave 32 rows
    __shared__ __align__(16) float mkf[2048];
    __shared__ float lsq[128];

    const int b  = blockIdx.z;
    const int h  = blockIdx.y;
    const int q0 = blockIdx.x * 128;

    const int tid  = threadIdx.x;
    const int lane = tid & 63;
    const int wid  = tid >> 6;
    const int l31  = lane & 31;
    const int hl   = lane >> 5;

    for (int i = tid; i < 2048; i += 256) mkf[i] = mask[b * 2048 + i] ? 1.f : 0.f;

    // Q B-frags (n = q = l31, k = d = db*16 + hl*8 + j), from global
    const unsigned short* qg =
        Q + (size_t)(b * 2048 + q0 + wid * 32 + l31) * 1024 + h * 64 + hl * 8;
    s16x8 qf[4];
#pragma unroll
    for (int db = 0; db < 4; db++) qf[db] = *(const s16x8*)(qg + db * 16);

    __syncthreads();
    const float mq = mkf[q0 + wid * 32 + l31];

    // staging: 512 chunks of 8 elems per array; thread t handles chunks t, t+256
    const int lk = (tid >> 3) * ST + (tid & 7) * 8;
    const unsigned short* gK = K  + (size_t)(b * 2048 + (tid >> 3)) * 1024 + h * 64 + (tid & 7) * 8;
    const unsigned short* gV = Vt + (size_t)(b * 1024 + h * 64 + (tid >> 3)) * 2048 + (tid & 7) * 8;

    float  lsum  = 0.f;
    f32x16 accO0 = (f32x16){0.f,0.f,0.f,0.f,0.f,0.f,0.f,0.f,0.f,0.f,0.f,0.f,0.f,0.f,0.f,0.f};
    f32x16 accO1 = accO0;

    unsigned short* plw = &Pl[wid * 32 * ST]; // this wave's P region

    for (int kt = 0; kt < 2048; kt += 64) {
        __syncthreads();
        *(u16x8*)&Kl[lk]           = *(const u16x8*)(gK + (size_t)kt * 1024);
        *(u16x8*)&Kl[lk + 32 * ST] = *(const u16x8*)(gK + (size_t)(kt + 32) * 1024);
        *(u16x8*)&Vl[lk]           = *(const u16x8*)(gV + kt);
        *(u16x8*)&Vl[lk + 32 * ST] = *(const u16x8*)(gV + kt + (size_t)32 * 2048);
        __syncthreads();

        // S^T for 2 key sub-tiles of 32
#pragma unroll
        for (int kt2 = 0; kt2 < 2; kt2++) {
            f32x16 st = (f32x16){0.f,0.f,0.f,0.f,0.f,0.f,0.f,0.f,
                                 0.f,0.f,0.f,0.f,0.f,0.f,0.f,0.f};
#pragma unroll
            for (int db = 0; db < 4; db++) {
                s16x8 kf = *(const s16x8*)&Kl[(kt2 * 32 + l31) * ST + db * 16 + hl * 8];
                st = MFMA32(kf, qf[db], st);
            }
            // mask + exp + pack; keys of reg-quad rq: kb..kb+3 (consecutive)
#pragma unroll
            for (int rq = 0; rq < 4; rq++) {
                int   kb = kt2 * 32 + 4 * hl + 8 * rq;
                f32x4 m4 = *(const f32x4*)&mkf[kt + kb];
                unsigned u[4];
#pragma unroll
                for (int r = 0; r < 4; r++) {
                    float e = __expf(st[rq * 4 + r]);
                    float p = e * (m4[r] * mq) + EPS;
                    lsum += p;
                    u[r] = __builtin_bit_cast(unsigned, p) + 0x8000u; // round-half-up
                }
                uint2 w;
                w.x = __builtin_amdgcn_perm(u[1], u[0], 0x07060302u);
                w.y = __builtin_amdgcn_perm(u[3], u[2], 0x07060302u);
                *(uint2*)&plw[l31 * ST + kb] = w;
            }
        }

        // PV: A = P[q][k], B = V^T[k][d] (from Vl[d][k])
#pragma unroll
        for (int kb = 0; kb < 4; kb++) {
            s16x8 pf  = *(const s16x8*)&plw[l31 * ST + kb * 16 + hl * 8];
            s16x8 vf0 = *(const s16x8*)&Vl[l31 * ST + kb * 16 + hl * 8];
            s16x8 vf1 = *(const s16x8*)&Vl[(32 + l31) * ST + kb * 16 + hl * 8];
            accO0 = MFMA32(pf, vf0, accO0);
            accO1 = MFMA32(pf, vf1, accO1);
        }
    }

    // finalize row sums: halves hold complementary key residues
    lsum += __shfl_xor(lsum, 32, 64);
    if (lane < 32) lsq[wid * 32 + l31] = lsum;

    // epilogue: O C-layout col = d = dc*32+l31, row = q = 4*hl+8*rq+r
#pragma unroll
    for (int dc = 0; dc < 2; dc++)
#pragma unroll
        for (int rq = 0; rq < 4; rq++) {
            f32x4 ls4 = *(const f32x4*)&lsq[wid * 32 + 4 * hl + 8 * rq];
#pragma unroll
            for (int r = 0; r < 4; r++) {
                int   qrow = 4 * hl + 8 * rq + r;
                float acc  = (dc == 0) ? accO0[rq * 4 + r] : accO1[rq * 4 + r];
                float val  = acc * __builtin_amdgcn_rcpf(ls4[r]);
                O[(size_t)(b * 2048 + q0 + wid * 32 + qrow) * 1024 + h * 64 +
                  dc * 32 + l31] = f2b(val);
            }
        }
}

// ---------------------------------------------------------------------------
extern "C" void kernel_launch(void* const* d_in, const int* in_sizes, int n_in,
                              void* d_out, int out_size, void* d_ws, size_t ws_size,
                              hipStream_t stream)
{
    const float* query = (const float*)d_in[0];
    const float* key_  = (const float*)d_in[1];
    const float* value = (const float*)d_in[2];
    const int*   mask  = (const int*)d_in[3];
    const float* Wq    = (const float*)d_in[4];
    const float* bq    = (const float*)d_in[5];
    const float* Wk    = (const float*)d_in[6];
    const float* bk    = (const float*)d_in[7];
    const float* Wv    = (const float*)d_in[8];
    const float* bv    = (const float*)d_in[9];
    const float* Wo    = (const float*)d_in[10];
    const float* bo    = (const float*)d_in[11];
    float* out = (float*)d_out;

    unsigned short* cvt = (unsigned short*)d_ws;
    unsigned short* Aq  = cvt;
    unsigned short* Ak  = cvt + M4;
    unsigned short* Av  = cvt + 2 * M4;
    unsigned short* Wqb = cvt + 3 * M4;
    unsigned short* Wkb = Wqb + M1;
    unsigned short* Wvb = Wkb + M1;
    unsigned short* Wob = Wvb + M1;
    unsigned short* Qb  = Wob + M1;
    unsigned short* Kb  = Qb + M4;
    unsigned short* Vt  = Kb + M4;
    unsigned short* Ab  = Vt + M4;

    CvtArgs ca;
    ca.src[0] = query; ca.src[1] = key_; ca.src[2] = value;
    ca.src[3] = Wq; ca.src[4] = Wk; ca.src[5] = Wv; ca.src[6] = Wo;
    ca.dst = cvt;
    cvt_bf16<<<dim3(8192), 256, 0, stream>>>(ca);

    GArgs ga;
    ga.A[0] = Aq;  ga.A[1] = Ak;  ga.A[2] = Av;
    ga.W[0] = Wqb; ga.W[1] = Wkb; ga.W[2] = Wvb;
    ga.bias[0] = bq; ga.bias[1] = bk; ga.bias[2] = bv;
    ga.C[0] = Qb; ga.C[1] = Kb; ga.C[2] = Vt;
    proj_gemm<<<dim3(8, 32, 3), 256, 0, stream>>>(ga);

    flash_attn<<<dim3(Ss / 128, Hh, Bb), 256, 0, stream>>>(Qb, Kb, Vt, mask, Ab);
    out_gemm<<<dim3(8, 32, 1), 256, 0, stream>>>(Ab, Wob, bo, out);
}

// Round 6
// 272.557 us; speedup vs baseline: 1.0010x; 1.0010x over previous
//
#include <hip/hip_runtime.h>

typedef __attribute__((ext_vector_type(4)))  float          f32x4;
typedef __attribute__((ext_vector_type(16))) float          f32x16;
typedef __attribute__((ext_vector_type(8)))  short          s16x8;
typedef __attribute__((ext_vector_type(4)))  unsigned short u16x4;
typedef __attribute__((ext_vector_type(8)))  unsigned short u16x8;

#define MFMA_BF16(a, b, c) __builtin_amdgcn_mfma_f32_16x16x32_bf16((a), (b), (c), 0, 0, 0)
#define MFMA32(a, b, c)    __builtin_amdgcn_mfma_f32_32x32x16_bf16((a), (b), (c), 0, 0, 0)

static constexpr int Bb = 2, Ss = 2048, Ee = 1024, Hh = 16, Dd = 64;
static constexpr size_t M4 = 4u * 1024 * 1024;
static constexpr size_t M1 = 1024 * 1024;

__device__ __forceinline__ unsigned short f2b(float f) {
    unsigned u = __builtin_bit_cast(unsigned, f);
    u += 0x7fffu + ((u >> 16) & 1u);
    return (unsigned short)(u >> 16);
}

__device__ __forceinline__ void gld_lds16(const unsigned short* g, unsigned short* l) {
    __builtin_amdgcn_global_load_lds(
        (const __attribute__((address_space(1))) unsigned int*)g,
        (__attribute__((address_space(3))) unsigned int*)l, 16, 0, 0);
}

// ---------------------------------------------------------------------------
// Convert fp32 inputs to bf16 workspace + mask -> float array.
// ---------------------------------------------------------------------------
struct CvtArgs { const float* src[7]; unsigned short* dst;
                 const int* mask; float* maskf; };

__global__ __launch_bounds__(256) void cvt_bf16(CvtArgs a)
{
    if (blockIdx.x == 8192) { // mask -> float (4096 elems)
#pragma unroll
        for (int j = 0; j < 16; j++) {
            int idx = threadIdx.x + j * 256;
            a.maskf[idx] = a.mask[idx] ? 1.f : 0.f;
        }
        return;
    }
    size_t i = ((size_t)blockIdx.x * 256 + threadIdx.x) * 8;
    int seg; size_t off;
    if (i < 3 * M4) { seg = (int)(i / M4);     off = i % M4; }
    else            { size_t j = i - 3 * M4;
                      seg = 3 + (int)(j / M1); off = j % M1; }
    const float* s = a.src[seg] + off;
    f32x4 x0 = *(const f32x4*)s;
    f32x4 x1 = *(const f32x4*)(s + 4);
    u16x8 o = (u16x8){f2b(x0[0]), f2b(x0[1]), f2b(x0[2]), f2b(x0[3]),
                      f2b(x1[0]), f2b(x1[1]), f2b(x1[2]), f2b(x1[3])};
    *(u16x8*)(a.dst + i) = o;
}

// ---------------------------------------------------------------------------
// bf16 GEMM, 128x128 tile, BK=64 via dual 32-wide LDS buffers (halves the
// barrier count per FLOP vs BK=32; keeps verified [row][32] DMA + frag maps).
// OUT_MODE: 0 fp32 [m][n]; 1 bf16 [m][n]; 2 bf16 V-transposed; 3 bf16 scaled
// by 0.125*log2(e) (Q path: folds attn scale + exp2 conversion).
// ---------------------------------------------------------------------------
template <int OUT_MODE>
__device__ __forceinline__ void gemm_bf16_body(const unsigned short* __restrict__ A,
                                               const unsigned short* __restrict__ W,
                                               const float* __restrict__ bias,
                                               void* __restrict__ Cv)
{
    __shared__ __align__(16) unsigned short Al0[128 * 32], Al1[128 * 32];
    __shared__ __align__(16) unsigned short Bl0[128 * 32], Bl1[128 * 32];

    const int tid  = threadIdx.x;
    const int lane = tid & 63;
    const int wid  = tid >> 6;
    const int quad = lane >> 4;
    const int lr   = lane & 15;
    const int wr   = (wid >> 1) * 64;
    const int wc   = (wid & 1) * 64;
    const int m0   = blockIdx.y * 128;
    const int n0   = blockIdx.x * 128;

    const int srow = wid * 32 + (lane >> 2);
    const int sk8  = (lane & 3) * 8;
    const unsigned short* gA = A + (size_t)(m0 + srow) * 1024 + sk8;
    const unsigned short* gW = W + (size_t)(n0 + srow) * 1024 + sk8;
    unsigned short* lA0 = &Al0[wid * 1024]; unsigned short* lA1 = &Al1[wid * 1024];
    unsigned short* lW0 = &Bl0[wid * 1024]; unsigned short* lW1 = &Bl1[wid * 1024];

    f32x4 acc[4][4];
#pragma unroll
    for (int i = 0; i < 4; i++)
#pragma unroll
        for (int j = 0; j < 4; j++) acc[i][j] = (f32x4){0.f, 0.f, 0.f, 0.f};

    for (int ks = 0; ks < 1024; ks += 64) {
        __syncthreads();
        gld_lds16(gA + ks,                   lA0);
        gld_lds16(gA + ks + 16 * 1024,       lA0 + 512);
        gld_lds16(gA + ks + 32,              lA1);
        gld_lds16(gA + ks + 32 + 16 * 1024,  lA1 + 512);
        gld_lds16(gW + ks,                   lW0);
        gld_lds16(gW + ks + 16 * 1024,       lW0 + 512);
        gld_lds16(gW + ks + 32,              lW1);
        gld_lds16(gW + ks + 32 + 16 * 1024,  lW1 + 512);
        __syncthreads();

#pragma unroll
        for (int sub = 0; sub < 2; sub++) {
            const unsigned short* Als = sub ? Al1 : Al0;
            const unsigned short* Bls = sub ? Bl1 : Bl0;
            s16x8 af[4], bf[4];
#pragma unroll
            for (int t = 0; t < 4; t++) {
                af[t] = *(const s16x8*)&Als[(wr + t * 16 + lr) * 32 + quad * 8];
                bf[t] = *(const s16x8*)&Bls[(wc + t * 16 + lr) * 32 + quad * 8];
            }
#pragma unroll
            for (int mt = 0; mt < 4; mt++)
#pragma unroll
                for (int nt = 0; nt < 4; nt++)
                    acc[mt][nt] = MFMA_BF16(af[mt], bf[nt], acc[mt][nt]);
        }
    }

#pragma unroll
    for (int mt = 0; mt < 4; mt++)
#pragma unroll
        for (int nt = 0; nt < 4; nt++) {
            int   col  = n0 + wc + nt * 16 + lr;
            float bcol = bias[col];
            int   rbase = m0 + wr + mt * 16 + quad * 4;
            if (OUT_MODE == 2) {
                int bb = rbase >> 11, s = rbase & 2047;
                u16x4 pk;
#pragma unroll
                for (int r = 0; r < 4; r++) pk[r] = f2b(acc[mt][nt][r] + bcol);
                *(u16x4*)&((unsigned short*)Cv)[((size_t)(bb * 1024 + col)) * 2048 + s] = pk;
            } else {
#pragma unroll
                for (int r = 0; r < 4; r++) {
                    float v = acc[mt][nt][r] + bcol;
                    if (OUT_MODE == 3) v *= 0.180336884f; // 0.125 * log2(e)
                    if (OUT_MODE == 0)
                        ((float*)Cv)[(size_t)(rbase + r) * 1024 + col] = v;
                    else
                        ((unsigned short*)Cv)[(size_t)(rbase + r) * 1024 + col] = f2b(v);
                }
            }
        }
}

struct GArgs {
    const unsigned short* A[3];
    const unsigned short* W[3];
    const float* bias[3];
    unsigned short* C[3];
};

__global__ __launch_bounds__(256) void proj_gemm(GArgs ga)
{
    int z = blockIdx.z;
    if (z == 2)      gemm_bf16_body<2>(ga.A[2], ga.W[2], ga.bias[2], ga.C[2]);
    else if (z == 1) gemm_bf16_body<1>(ga.A[1], ga.W[1], ga.bias[1], ga.C[1]);
    else             gemm_bf16_body<3>(ga.A[0], ga.W[0], ga.bias[0], ga.C[0]);
}

__global__ __launch_bounds__(256) void out_gemm(const unsigned short* __restrict__ A,
                                                const unsigned short* __restrict__ W,
                                                const float* __restrict__ bias,
                                                float* __restrict__ C)
{
    gemm_bf16_body<0>(A, W, bias, C);
}

// ---------------------------------------------------------------------------
// Flash attention v7: 32x32 MFMA with quarter-split waves for full occupancy.
// Block = (b, h, 64 q), 4 waves; wave wid: qh = wid&1 (q-half), kh = wid>>1
// (key-half for S^T, d-half for PV). Grid 1024 blocks -> 4 blocks/CU x 4
// waves = 16 waves/CU (R5 was grid-limited to 8).
//  - S^T = K·Q^T quarter per wave; C-layout reg-quads = 4 consecutive keys ->
//    packed b64 P-writes straight into [q][k] = PV A-layout.
//  - p = exp2(st)·mk·mq + 2^-30 (scale 0.125·log2e folded into Q projection).
//  - masks from precomputed global float array (L2-hot), no LDS staging.
//  - 3 barriers/tile (extra one: cross-wave P sharing).
// ---------------------------------------------------------------------------
__global__ __launch_bounds__(256)
void flash_attn(const unsigned short* __restrict__ Q,
                const unsigned short* __restrict__ K,
                const unsigned short* __restrict__ Vt,
                const float* __restrict__ maskf,
                unsigned short* __restrict__ O)
{
    constexpr int   ST  = 76;               // 152 B row stride: 2-way banks max
    constexpr float EPS = 9.31322575e-10f;  // 2^-30
    __shared__ __align__(16) unsigned short Kl[64 * ST]; // [key][d]
    __shared__ __align__(16) unsigned short Vl[64 * ST]; // [d][key]
    __shared__ __align__(16) unsigned short Pl[64 * ST]; // [q][key]
    __shared__ float lsq[4][32];

    const int b  = blockIdx.z;
    const int h  = blockIdx.y;
    const int q0 = blockIdx.x * 64;

    const int tid  = threadIdx.x;
    const int lane = tid & 63;
    const int wid  = tid >> 6;
    const int l31  = lane & 31;
    const int hl   = lane >> 5;
    const int qh   = wid & 1;
    const int kh   = wid >> 1;

    // Q B-frags (n = q = qh*32+l31, k = d = db*16 + hl*8 + j)
    const unsigned short* qg =
        Q + (size_t)(b * 2048 + q0 + qh * 32 + l31) * 1024 + h * 64 + hl * 8;
    s16x8 qf[4];
#pragma unroll
    for (int db = 0; db < 4; db++) qf[db] = *(const s16x8*)(qg + db * 16);

    const float  mq  = maskf[b * 2048 + q0 + qh * 32 + l31];
    const float* mkp = maskf + b * 2048;

    // staging: thread t -> rows (t>>3), (t>>3)+32; chunk (t&7)*8
    const int lk = (tid >> 3) * ST + (tid & 7) * 8;
    const unsigned short* gK = K  + (size_t)(b * 2048 + (tid >> 3)) * 1024 + h * 64 + (tid & 7) * 8;
    const unsigned short* gV = Vt + (size_t)(b * 1024 + h * 64 + (tid >> 3)) * 2048 + (tid & 7) * 8;

    float  lsum = 0.f;
    f32x16 accO = (f32x16){0.f,0.f,0.f,0.f,0.f,0.f,0.f,0.f,
                           0.f,0.f,0.f,0.f,0.f,0.f,0.f,0.f};

    for (int kt = 0; kt < 2048; kt += 64) {
        __syncthreads();
        *(u16x8*)&Kl[lk]           = *(const u16x8*)(gK + (size_t)kt * 1024);
        *(u16x8*)&Kl[lk + 32 * ST] = *(const u16x8*)(gK + (size_t)(kt + 32) * 1024);
        *(u16x8*)&Vl[lk]           = *(const u16x8*)(gV + kt);
        *(u16x8*)&Vl[lk + 32 * ST] = *(const u16x8*)(gV + kt + (size_t)32 * 2048);
        __syncthreads();

        // S^T quarter: keys kh*32.., q qh*32..
        f32x16 st = (f32x16){0.f,0.f,0.f,0.f,0.f,0.f,0.f,0.f,
                             0.f,0.f,0.f,0.f,0.f,0.f,0.f,0.f};
#pragma unroll
        for (int db = 0; db < 4; db++) {
            s16x8 kf = *(const s16x8*)&Kl[(kh * 32 + l31) * ST + db * 16 + hl * 8];
            st = MFMA32(kf, qf[db], st);
        }
        // exp2 + mask + pack; reg-quad rq covers keys kb..kb+3 (consecutive)
#pragma unroll
        for (int rq = 0; rq < 4; rq++) {
            int   kb = 4 * hl + 8 * rq; // within the 32-key half
            f32x4 m4 = *(const f32x4*)&mkp[kt + kh * 32 + kb];
            unsigned u[4];
#pragma unroll
            for (int r = 0; r < 4; r++) {
                float e = __builtin_amdgcn_exp2f(st[rq * 4 + r]);
                float p = e * (m4[r] * mq) + EPS;
                lsum += p;
                u[r] = __builtin_bit_cast(unsigned, p) + 0x8000u;
            }
            uint2 w;
            w.x = __builtin_amdgcn_perm(u[1], u[0], 0x07060302u);
            w.y = __builtin_amdgcn_perm(u[3], u[2], 0x07060302u);
            *(uint2*)&Pl[(qh * 32 + l31) * ST + kh * 32 + kb] = w;
        }
        __syncthreads(); // P quarters complete before cross-wave PV reads

        // PV quarter: q qh, d kh; A = P[q][64k], B = V^T[k][d] (Vl is [d][k])
#pragma unroll
        for (int ks = 0; ks < 4; ks++) {
            s16x8 pf = *(const s16x8*)&Pl[(qh * 32 + l31) * ST + ks * 16 + hl * 8];
            s16x8 vf = *(const s16x8*)&Vl[(kh * 32 + l31) * ST + ks * 16 + hl * 8];
            accO = MFMA32(pf, vf, accO);
        }
    }

    // row sums: in-lane over its quarter; combine hl halves, then kh pairs
    lsum += __shfl_xor(lsum, 32, 64);
    lsq[wid][l31] = lsum;
    __syncthreads();

    // epilogue: O C-layout col = d = kh*32+l31, row = q = qh*32 + 4hl+8rq+r
#pragma unroll
    for (int rq = 0; rq < 4; rq++) {
        int   qr = 4 * hl + 8 * rq;
        f32x4 lA = *(const f32x4*)&lsq[qh][qr];
        f32x4 lB = *(const f32x4*)&lsq[qh + 2][qr];
#pragma unroll
        for (int r = 0; r < 4; r++) {
            float val = accO[rq * 4 + r] * __builtin_amdgcn_rcpf(lA[r] + lB[r]);
            O[(size_t)(b * 2048 + q0 + qh * 32 + qr + r) * 1024 + h * 64 +
              kh * 32 + l31] = f2b(val);
        }
    }
}

// ---------------------------------------------------------------------------
extern "C" void kernel_launch(void* const* d_in, const int* in_sizes, int n_in,
                              void* d_out, int out_size, void* d_ws, size_t ws_size,
                              hipStream_t stream)
{
    const float* query = (const float*)d_in[0];
    const float* key_  = (const float*)d_in[1];
    const float* value = (const float*)d_in[2];
    const int*   mask  = (const int*)d_in[3];
    const float* Wq    = (const float*)d_in[4];
    const float* bq    = (const float*)d_in[5];
    const float* Wk    = (const float*)d_in[6];
    const float* bk    = (const float*)d_in[7];
    const float* Wv    = (const float*)d_in[8];
    const float* bv    = (const float*)d_in[9];
    const float* Wo    = (const float*)d_in[10];
    const float* bo    = (const float*)d_in[11];
    float* out = (float*)d_out;

    unsigned short* cvt = (unsigned short*)d_ws;
    unsigned short* Aq  = cvt;
    unsigned short* Ak  = cvt + M4;
    unsigned short* Av  = cvt + 2 * M4;
    unsigned short* Wqb = cvt + 3 * M4;
    unsigned short* Wkb = Wqb + M1;
    unsigned short* Wvb = Wkb + M1;
    unsigned short* Wob = Wvb + M1;
    unsigned short* Qb  = Wob + M1;
    unsigned short* Kb  = Qb + M4;
    unsigned short* Vt  = Kb + M4;
    unsigned short* Ab  = Vt + M4;
    float*          mkf = (float*)(Ab + M4);

    CvtArgs ca;
    ca.src[0] = query; ca.src[1] = key_; ca.src[2] = value;
    ca.src[3] = Wq; ca.src[4] = Wk; ca.src[5] = Wv; ca.src[6] = Wo;
    ca.dst = cvt; ca.mask = mask; ca.maskf = mkf;
    cvt_bf16<<<dim3(8193), 256, 0, stream>>>(ca);

    GArgs ga;
    ga.A[0] = Aq;  ga.A[1] = Ak;  ga.A[2] = Av;
    ga.W[0] = Wqb; ga.W[1] = Wkb; ga.W[2] = Wvb;
    ga.bias[0] = bq; ga.bias[1] = bk; ga.bias[2] = bv;
    ga.C[0] = Qb; ga.C[1] = Kb; ga.C[2] = Vt;
    proj_gemm<<<dim3(8, 32, 3), 256, 0, stream>>>(ga);

    flash_attn<<<dim3(Ss / 64, Hh, Bb), 256, 0, stream>>>(Qb, Kb, Vt, mkf, Ab);
    out_gemm<<<dim3(8, 32, 1), 256, 0, stream>>>(Ab, Wob, bo, out);
}

// Round 7
// 247.293 us; speedup vs baseline: 1.1033x; 1.1022x over previous
//
#include <hip/hip_runtime.h>

typedef __attribute__((ext_vector_type(4)))  float          f32x4;
typedef __attribute__((ext_vector_type(16))) float          f32x16;
typedef __attribute__((ext_vector_type(8)))  short          s16x8;
typedef __attribute__((ext_vector_type(4)))  unsigned short u16x4;
typedef __attribute__((ext_vector_type(8)))  unsigned short u16x8;

#define MFMA_BF16(a, b, c) __builtin_amdgcn_mfma_f32_16x16x32_bf16((a), (b), (c), 0, 0, 0)
#define MFMA32(a, b, c)    __builtin_amdgcn_mfma_f32_32x32x16_bf16((a), (b), (c), 0, 0, 0)

static constexpr int Bb = 2, Ss = 2048, Ee = 1024, Hh = 16, Dd = 64;
static constexpr size_t M4 = 4u * 1024 * 1024;
static constexpr size_t M1 = 1024 * 1024;

__device__ __forceinline__ unsigned short f2b(float f) {
    unsigned u = __builtin_bit_cast(unsigned, f);
    u += 0x7fffu + ((u >> 16) & 1u);
    return (unsigned short)(u >> 16);
}

__device__ __forceinline__ void gld_lds16(const unsigned short* g, unsigned short* l) {
    __builtin_amdgcn_global_load_lds(
        (const __attribute__((address_space(1))) unsigned int*)g,
        (__attribute__((address_space(3))) unsigned int*)l, 16, 0, 0);
}

// ---------------------------------------------------------------------------
// Convert fp32 inputs to bf16 workspace + mask -> float array.
// ---------------------------------------------------------------------------
struct CvtArgs { const float* src[7]; unsigned short* dst;
                 const int* mask; float* maskf; };

__global__ __launch_bounds__(256) void cvt_bf16(CvtArgs a)
{
    if (blockIdx.x == 8192) { // mask -> float (4096 elems)
#pragma unroll
        for (int j = 0; j < 16; j++) {
            int idx = threadIdx.x + j * 256;
            a.maskf[idx] = a.mask[idx] ? 1.f : 0.f;
        }
        return;
    }
    size_t i = ((size_t)blockIdx.x * 256 + threadIdx.x) * 8;
    int seg; size_t off;
    if (i < 3 * M4) { seg = (int)(i / M4);     off = i % M4; }
    else            { size_t j = i - 3 * M4;
                      seg = 3 + (int)(j / M1); off = j % M1; }
    const float* s = a.src[seg] + off;
    f32x4 x0 = *(const f32x4*)s;
    f32x4 x1 = *(const f32x4*)(s + 4);
    u16x8 o = (u16x8){f2b(x0[0]), f2b(x0[1]), f2b(x0[2]), f2b(x0[3]),
                      f2b(x1[0]), f2b(x1[1]), f2b(x1[2]), f2b(x1[3])};
    *(u16x8*)(a.dst + i) = o;
}

// ---------------------------------------------------------------------------
// bf16 GEMM, 128x128 tile, BK=32 (R4 structure — BK=64 regressed ~24 µs in R6).
// OUT_MODE: 0 fp32 [m][n]; 1 bf16 [m][n]; 2 bf16 V-transposed; 3 bf16 scaled
// by 0.125*log2(e) (Q path: folds attn scale + exp->exp2 conversion).
// ---------------------------------------------------------------------------
template <int OUT_MODE>
__device__ __forceinline__ void gemm_bf16_body(const unsigned short* __restrict__ A,
                                               const unsigned short* __restrict__ W,
                                               const float* __restrict__ bias,
                                               void* __restrict__ Cv)
{
    __shared__ __align__(16) unsigned short Al[128 * 32];
    __shared__ __align__(16) unsigned short Bl[128 * 32];

    const int tid  = threadIdx.x;
    const int lane = tid & 63;
    const int wid  = tid >> 6;
    const int quad = lane >> 4;
    const int lr   = lane & 15;
    const int wr   = (wid >> 1) * 64;
    const int wc   = (wid & 1) * 64;
    const int m0   = blockIdx.y * 128;
    const int n0   = blockIdx.x * 128;

    const int srow = wid * 32 + (lane >> 2);
    const int sk8  = (lane & 3) * 8;
    const unsigned short* gA = A + (size_t)(m0 + srow) * 1024 + sk8;
    const unsigned short* gW = W + (size_t)(n0 + srow) * 1024 + sk8;
    unsigned short* lA = &Al[wid * 1024];
    unsigned short* lW = &Bl[wid * 1024];

    f32x4 acc[4][4];
#pragma unroll
    for (int i = 0; i < 4; i++)
#pragma unroll
        for (int j = 0; j < 4; j++) acc[i][j] = (f32x4){0.f, 0.f, 0.f, 0.f};

    for (int ks = 0; ks < 1024; ks += 32) {
        __syncthreads();
        gld_lds16(gA + ks,              lA);
        gld_lds16(gA + ks + 16 * 1024,  lA + 512);
        gld_lds16(gW + ks,              lW);
        gld_lds16(gW + ks + 16 * 1024,  lW + 512);
        __syncthreads();

        s16x8 af[4], bf[4];
#pragma unroll
        for (int t = 0; t < 4; t++) {
            af[t] = *(const s16x8*)&Al[(wr + t * 16 + lr) * 32 + quad * 8];
            bf[t] = *(const s16x8*)&Bl[(wc + t * 16 + lr) * 32 + quad * 8];
        }
#pragma unroll
        for (int mt = 0; mt < 4; mt++)
#pragma unroll
            for (int nt = 0; nt < 4; nt++)
                acc[mt][nt] = MFMA_BF16(af[mt], bf[nt], acc[mt][nt]);
    }

#pragma unroll
    for (int mt = 0; mt < 4; mt++)
#pragma unroll
        for (int nt = 0; nt < 4; nt++) {
            int   col  = n0 + wc + nt * 16 + lr;
            float bcol = bias[col];
            int   rbase = m0 + wr + mt * 16 + quad * 4;
            if (OUT_MODE == 2) {
                int bb = rbase >> 11, s = rbase & 2047;
                u16x4 pk;
#pragma unroll
                for (int r = 0; r < 4; r++) pk[r] = f2b(acc[mt][nt][r] + bcol);
                *(u16x4*)&((unsigned short*)Cv)[((size_t)(bb * 1024 + col)) * 2048 + s] = pk;
            } else {
#pragma unroll
                for (int r = 0; r < 4; r++) {
                    float v = acc[mt][nt][r] + bcol;
                    if (OUT_MODE == 3) v *= 0.180336884f; // 0.125 * log2(e)
                    if (OUT_MODE == 0)
                        ((float*)Cv)[(size_t)(rbase + r) * 1024 + col] = v;
                    else
                        ((unsigned short*)Cv)[(size_t)(rbase + r) * 1024 + col] = f2b(v);
                }
            }
        }
}

struct GArgs {
    const unsigned short* A[3];
    const unsigned short* W[3];
    const float* bias[3];
    unsigned short* C[3];
};

__global__ __launch_bounds__(256) void proj_gemm(GArgs ga)
{
    int z = blockIdx.z;
    if (z == 2)      gemm_bf16_body<2>(ga.A[2], ga.W[2], ga.bias[2], ga.C[2]);
    else if (z == 1) gemm_bf16_body<1>(ga.A[1], ga.W[1], ga.bias[1], ga.C[1]);
    else             gemm_bf16_body<3>(ga.A[0], ga.W[0], ga.bias[0], ga.C[0]);
}

__global__ __launch_bounds__(256) void out_gemm(const unsigned short* __restrict__ A,
                                                const unsigned short* __restrict__ W,
                                                const float* __restrict__ bias,
                                                float* __restrict__ C)
{
    gemm_bf16_body<0>(A, W, bias, C);
}

// ---------------------------------------------------------------------------
// Flash attention v8: R6 body + XCD-aware swizzle.
// Grid = 1024 flat blocks. xcd = id&7, local = id>>3; each XCD owns 4 (b,h)
// pairs (2 MB K+V -> L2-resident), all 32 q-blocks of a pair stay on that
// XCD (flat ids congruent mod 8 under round-robin dispatch). Targets the
// 68 MB vs 24 MB ideal FETCH_SIZE seen in R6 and the HBM-latency staging
// drains behind each tile barrier.
// ---------------------------------------------------------------------------
__global__ __launch_bounds__(256)
void flash_attn(const unsigned short* __restrict__ Q,
                const unsigned short* __restrict__ K,
                const unsigned short* __restrict__ Vt,
                const float* __restrict__ maskf,
                unsigned short* __restrict__ O)
{
    constexpr int   ST  = 76;               // 152 B row stride: conflict-free (R6: 0)
    constexpr float EPS = 9.31322575e-10f;  // 2^-30
    __shared__ __align__(16) unsigned short Kl[64 * ST]; // [key][d]
    __shared__ __align__(16) unsigned short Vl[64 * ST]; // [d][key]
    __shared__ __align__(16) unsigned short Pl[64 * ST]; // [q][key]
    __shared__ float lsq[4][32];

    // XCD-aware decode: 4 (b,h) pairs per XCD, 32 q-blocks per pair
    const int id    = blockIdx.x;
    const int xcd   = id & 7;
    const int local = id >> 3;
    const int pair  = xcd * 4 + (local >> 5);
    const int b     = pair >> 4;
    const int h     = pair & 15;
    const int q0    = (local & 31) * 64;

    const int tid  = threadIdx.x;
    const int lane = tid & 63;
    const int wid  = tid >> 6;
    const int l31  = lane & 31;
    const int hl   = lane >> 5;
    const int qh   = wid & 1;
    const int kh   = wid >> 1;

    // Q B-frags (n = q = qh*32+l31, k = d = db*16 + hl*8 + j)
    const unsigned short* qg =
        Q + (size_t)(b * 2048 + q0 + qh * 32 + l31) * 1024 + h * 64 + hl * 8;
    s16x8 qf[4];
#pragma unroll
    for (int db = 0; db < 4; db++) qf[db] = *(const s16x8*)(qg + db * 16);

    const float  mq  = maskf[b * 2048 + q0 + qh * 32 + l31];
    const float* mkp = maskf + b * 2048;

    // staging: thread t -> rows (t>>3), (t>>3)+32; chunk (t&7)*8
    const int lk = (tid >> 3) * ST + (tid & 7) * 8;
    const unsigned short* gK = K  + (size_t)(b * 2048 + (tid >> 3)) * 1024 + h * 64 + (tid & 7) * 8;
    const unsigned short* gV = Vt + (size_t)(b * 1024 + h * 64 + (tid >> 3)) * 2048 + (tid & 7) * 8;

    float  lsum = 0.f;
    f32x16 accO = (f32x16){0.f,0.f,0.f,0.f,0.f,0.f,0.f,0.f,
                           0.f,0.f,0.f,0.f,0.f,0.f,0.f,0.f};

    for (int kt = 0; kt < 2048; kt += 64) {
        __syncthreads();
        *(u16x8*)&Kl[lk]           = *(const u16x8*)(gK + (size_t)kt * 1024);
        *(u16x8*)&Kl[lk + 32 * ST] = *(const u16x8*)(gK + (size_t)(kt + 32) * 1024);
        *(u16x8*)&Vl[lk]           = *(const u16x8*)(gV + kt);
        *(u16x8*)&Vl[lk + 32 * ST] = *(const u16x8*)(gV + kt + (size_t)32 * 2048);
        __syncthreads();

        // S^T quarter: keys kh*32.., q qh*32..
        f32x16 st = (f32x16){0.f,0.f,0.f,0.f,0.f,0.f,0.f,0.f,
                             0.f,0.f,0.f,0.f,0.f,0.f,0.f,0.f};
#pragma unroll
        for (int db = 0; db < 4; db++) {
            s16x8 kf = *(const s16x8*)&Kl[(kh * 32 + l31) * ST + db * 16 + hl * 8];
            st = MFMA32(kf, qf[db], st);
        }
        // exp2 + mask + pack; reg-quad rq covers keys kb..kb+3 (consecutive)
#pragma unroll
        for (int rq = 0; rq < 4; rq++) {
            int   kb = 4 * hl + 8 * rq; // within the 32-key half
            f32x4 m4 = *(const f32x4*)&mkp[kt + kh * 32 + kb];
            unsigned u[4];
#pragma unroll
            for (int r = 0; r < 4; r++) {
                float e = __builtin_amdgcn_exp2f(st[rq * 4 + r]);
                float p = e * (m4[r] * mq) + EPS;
                lsum += p;
                u[r] = __builtin_bit_cast(unsigned, p) + 0x8000u;
            }
            uint2 w;
            w.x = __builtin_amdgcn_perm(u[1], u[0], 0x07060302u);
            w.y = __builtin_amdgcn_perm(u[3], u[2], 0x07060302u);
            *(uint2*)&Pl[(qh * 32 + l31) * ST + kh * 32 + kb] = w;
        }
        __syncthreads(); // P quarters complete before cross-wave PV reads

        // PV quarter: q qh, d kh; A = P[q][64k], B = V^T[k][d] (Vl is [d][k])
#pragma unroll
        for (int ks = 0; ks < 4; ks++) {
            s16x8 pf = *(const s16x8*)&Pl[(qh * 32 + l31) * ST + ks * 16 + hl * 8];
            s16x8 vf = *(const s16x8*)&Vl[(kh * 32 + l31) * ST + ks * 16 + hl * 8];
            accO = MFMA32(pf, vf, accO);
        }
    }

    // row sums: in-lane over its quarter; combine hl halves, then kh pairs
    lsum += __shfl_xor(lsum, 32, 64);
    lsq[wid][l31] = lsum;
    __syncthreads();

    // epilogue: O C-layout col = d = kh*32+l31, row = q = qh*32 + 4hl+8rq+r
#pragma unroll
    for (int rq = 0; rq < 4; rq++) {
        int   qr = 4 * hl + 8 * rq;
        f32x4 lA = *(const f32x4*)&lsq[qh][qr];
        f32x4 lB = *(const f32x4*)&lsq[qh + 2][qr];
#pragma unroll
        for (int r = 0; r < 4; r++) {
            float val = accO[rq * 4 + r] * __builtin_amdgcn_rcpf(lA[r] + lB[r]);
            O[(size_t)(b * 2048 + q0 + qh * 32 + qr + r) * 1024 + h * 64 +
              kh * 32 + l31] = f2b(val);
        }
    }
}

// ---------------------------------------------------------------------------
extern "C" void kernel_launch(void* const* d_in, const int* in_sizes, int n_in,
                              void* d_out, int out_size, void* d_ws, size_t ws_size,
                              hipStream_t stream)
{
    const float* query = (const float*)d_in[0];
    const float* key_  = (const float*)d_in[1];
    const float* value = (const float*)d_in[2];
    const int*   mask  = (const int*)d_in[3];
    const float* Wq    = (const float*)d_in[4];
    const float* bq    = (const float*)d_in[5];
    const float* Wk    = (const float*)d_in[6];
    const float* bk    = (const float*)d_in[7];
    const float* Wv    = (const float*)d_in[8];
    const float* bv    = (const float*)d_in[9];
    const float* Wo    = (const float*)d_in[10];
    const float* bo    = (const float*)d_in[11];
    float* out = (float*)d_out;

    unsigned short* cvt = (unsigned short*)d_ws;
    unsigned short* Aq  = cvt;
    unsigned short* Ak  = cvt + M4;
    unsigned short* Av  = cvt + 2 * M4;
    unsigned short* Wqb = cvt + 3 * M4;
    unsigned short* Wkb = Wqb + M1;
    unsigned short* Wvb = Wkb + M1;
    unsigned short* Wob = Wvb + M1;
    unsigned short* Qb  = Wob + M1;
    unsigned short* Kb  = Qb + M4;
    unsigned short* Vt  = Kb + M4;
    unsigned short* Ab  = Vt + M4;
    float*          mkf = (float*)(Ab + M4);

    CvtArgs ca;
    ca.src[0] = query; ca.src[1] = key_; ca.src[2] = value;
    ca.src[3] = Wq; ca.src[4] = Wk; ca.src[5] = Wv; ca.src[6] = Wo;
    ca.dst = cvt; ca.mask = mask; ca.maskf = mkf;
    cvt_bf16<<<dim3(8193), 256, 0, stream>>>(ca);

    GArgs ga;
    ga.A[0] = Aq;  ga.A[1] = Ak;  ga.A[2] = Av;
    ga.W[0] = Wqb; ga.W[1] = Wkb; ga.W[2] = Wvb;
    ga.bias[0] = bq; ga.bias[1] = bk; ga.bias[2] = bv;
    ga.C[0] = Qb; ga.C[1] = Kb; ga.C[2] = Vt;
    proj_gemm<<<dim3(8, 32, 3), 256, 0, stream>>>(ga);

    flash_attn<<<dim3(1024), 256, 0, stream>>>(Qb, Kb, Vt, mkf, Ab);
    out_gemm<<<dim3(8, 32, 1), 256, 0, stream>>>(Ab, Wob, bo, out);
}

// Round 8
// 236.226 us; speedup vs baseline: 1.1550x; 1.0469x over previous
//
#include <hip/hip_runtime.h>

typedef __attribute__((ext_vector_type(4)))  float          f32x4;
typedef __attribute__((ext_vector_type(16))) float          f32x16;
typedef __attribute__((ext_vector_type(8)))  short          s16x8;
typedef __attribute__((ext_vector_type(4)))  unsigned short u16x4;
typedef __attribute__((ext_vector_type(8)))  unsigned short u16x8;

#define MFMA_BF16(a, b, c) __builtin_amdgcn_mfma_f32_16x16x32_bf16((a), (b), (c), 0, 0, 0)
#define MFMA32(a, b, c)    __builtin_amdgcn_mfma_f32_32x32x16_bf16((a), (b), (c), 0, 0, 0)

static constexpr int Bb = 2, Ss = 2048, Ee = 1024, Hh = 16, Dd = 64;
static constexpr size_t M4 = 4u * 1024 * 1024;
static constexpr size_t M1 = 1024 * 1024;

__device__ __forceinline__ unsigned short f2b(float f) {
    unsigned u = __builtin_bit_cast(unsigned, f);
    u += 0x7fffu + ((u >> 16) & 1u);
    return (unsigned short)(u >> 16);
}

__device__ __forceinline__ void gld_lds16(const unsigned short* g, unsigned short* l) {
    __builtin_amdgcn_global_load_lds(
        (const __attribute__((address_space(1))) unsigned int*)g,
        (__attribute__((address_space(3))) unsigned int*)l, 16, 0, 0);
}

// ---------------------------------------------------------------------------
// Convert fp32 inputs to bf16 workspace + mask -> float array.
// ---------------------------------------------------------------------------
struct CvtArgs { const float* src[7]; unsigned short* dst;
                 const int* mask; float* maskf; };

__global__ __launch_bounds__(256) void cvt_bf16(CvtArgs a)
{
    if (blockIdx.x == 8192) { // mask -> float (4096 elems)
#pragma unroll
        for (int j = 0; j < 16; j++) {
            int idx = threadIdx.x + j * 256;
            a.maskf[idx] = a.mask[idx] ? 1.f : 0.f;
        }
        return;
    }
    size_t i = ((size_t)blockIdx.x * 256 + threadIdx.x) * 8;
    int seg; size_t off;
    if (i < 3 * M4) { seg = (int)(i / M4);     off = i % M4; }
    else            { size_t j = i - 3 * M4;
                      seg = 3 + (int)(j / M1); off = j % M1; }
    const float* s = a.src[seg] + off;
    f32x4 x0 = *(const f32x4*)s;
    f32x4 x1 = *(const f32x4*)(s + 4);
    u16x8 o = (u16x8){f2b(x0[0]), f2b(x0[1]), f2b(x0[2]), f2b(x0[3]),
                      f2b(x1[0]), f2b(x1[1]), f2b(x1[2]), f2b(x1[3])};
    *(u16x8*)(a.dst + i) = o;
}

// ---------------------------------------------------------------------------
// bf16 GEMM body, 128x128 tile, BK=32 (R4 structure).
// OUT_MODE: 0 fp32 [m][n]; 1 bf16 [m][n]; 2 bf16 V-transposed; 3 bf16 scaled
// by 0.125*log2(e) (Q path: folds attn scale + exp->exp2 conversion).
// ---------------------------------------------------------------------------
template <int OUT_MODE>
__device__ __forceinline__ void gemm_bf16_body(const unsigned short* __restrict__ A,
                                               const unsigned short* __restrict__ W,
                                               const float* __restrict__ bias,
                                               void* __restrict__ Cv,
                                               int m0, int n0)
{
    __shared__ __align__(16) unsigned short Al[128 * 32];
    __shared__ __align__(16) unsigned short Bl[128 * 32];

    const int tid  = threadIdx.x;
    const int lane = tid & 63;
    const int wid  = tid >> 6;
    const int quad = lane >> 4;
    const int lr   = lane & 15;
    const int wr   = (wid >> 1) * 64;
    const int wc   = (wid & 1) * 64;

    const int srow = wid * 32 + (lane >> 2);
    const int sk8  = (lane & 3) * 8;
    const unsigned short* gA = A + (size_t)(m0 + srow) * 1024 + sk8;
    const unsigned short* gW = W + (size_t)(n0 + srow) * 1024 + sk8;
    unsigned short* lA = &Al[wid * 1024];
    unsigned short* lW = &Bl[wid * 1024];

    f32x4 acc[4][4];
#pragma unroll
    for (int i = 0; i < 4; i++)
#pragma unroll
        for (int j = 0; j < 4; j++) acc[i][j] = (f32x4){0.f, 0.f, 0.f, 0.f};

    for (int ks = 0; ks < 1024; ks += 32) {
        __syncthreads();
        gld_lds16(gA + ks,              lA);
        gld_lds16(gA + ks + 16 * 1024,  lA + 512);
        gld_lds16(gW + ks,              lW);
        gld_lds16(gW + ks + 16 * 1024,  lW + 512);
        __syncthreads();

        s16x8 af[4], bf[4];
#pragma unroll
        for (int t = 0; t < 4; t++) {
            af[t] = *(const s16x8*)&Al[(wr + t * 16 + lr) * 32 + quad * 8];
            bf[t] = *(const s16x8*)&Bl[(wc + t * 16 + lr) * 32 + quad * 8];
        }
#pragma unroll
        for (int mt = 0; mt < 4; mt++)
#pragma unroll
            for (int nt = 0; nt < 4; nt++)
                acc[mt][nt] = MFMA_BF16(af[mt], bf[nt], acc[mt][nt]);
    }

#pragma unroll
    for (int mt = 0; mt < 4; mt++)
#pragma unroll
        for (int nt = 0; nt < 4; nt++) {
            int   col  = n0 + wc + nt * 16 + lr;
            float bcol = bias[col];
            int   rbase = m0 + wr + mt * 16 + quad * 4;
            if (OUT_MODE == 2) {
                int bb = rbase >> 11, s = rbase & 2047;
                u16x4 pk;
#pragma unroll
                for (int r = 0; r < 4; r++) pk[r] = f2b(acc[mt][nt][r] + bcol);
                *(u16x4*)&((unsigned short*)Cv)[((size_t)(bb * 1024 + col)) * 2048 + s] = pk;
            } else {
#pragma unroll
                for (int r = 0; r < 4; r++) {
                    float v = acc[mt][nt][r] + bcol;
                    if (OUT_MODE == 3) v *= 0.180336884f; // 0.125 * log2(e)
                    ((unsigned short*)Cv)[(size_t)(rbase + r) * 1024 + col] = f2b(v);
                }
            }
        }
}

struct GArgs {
    const unsigned short* A[3];
    const unsigned short* W[3];
    const float* bias[3];
    unsigned short* C[3];
};

// XCD-band swizzle: 1D grid 768. xcd = id&7 owns a 512-row A-band for ALL
// n-tiles and all z; dispatch rounds (32 blocks/XCD each) serialize z, so the
// per-XCD L2 working set is 1 MB A-band + 2 MB W = 3 MB < 4 MiB (was: entire
// 8 MB A x 3 z-arrays thrashing L2 -> every staging drain at L3/HBM latency).
__global__ __launch_bounds__(256) void proj_gemm(GArgs ga)
{
    const int id  = blockIdx.x;
    const int xcd = id & 7;
    const int t   = id >> 3;        // 0..95
    const int z   = t >> 5;         // one z per dispatch round
    const int tt  = t & 31;
    const int n0  = (tt & 7) * 128;
    const int m0  = (xcd * 4 + (tt >> 3)) * 128;

    if (z == 2)      gemm_bf16_body<2>(ga.A[2], ga.W[2], ga.bias[2], ga.C[2], m0, n0);
    else if (z == 1) gemm_bf16_body<1>(ga.A[1], ga.W[1], ga.bias[1], ga.C[1], m0, n0);
    else             gemm_bf16_body<3>(ga.A[0], ga.W[0], ga.bias[0], ga.C[0], m0, n0);
}

// ---------------------------------------------------------------------------
// out GEMM: 128x64 tiles -> grid 512 (2 blocks/CU; was 256 = 1/CU with no
// latency hiding). Same XCD band swizzle (1 MB A-band + 2 MB W per XCD).
// ---------------------------------------------------------------------------
__global__ __launch_bounds__(256)
void out_gemm(const unsigned short* __restrict__ A,
              const unsigned short* __restrict__ W,
              const float* __restrict__ bias,
              float* __restrict__ C)
{
    __shared__ __align__(16) unsigned short Al[128 * 32];
    __shared__ __align__(16) unsigned short Bl[64 * 32];

    const int id  = blockIdx.x;
    const int xcd = id & 7;
    const int t   = id >> 3;            // 0..63
    const int n0  = (t & 15) * 64;
    const int m0  = (xcd * 4 + (t >> 4)) * 128;

    const int tid  = threadIdx.x;
    const int lane = tid & 63;
    const int wid  = tid >> 6;
    const int quad = lane >> 4;
    const int lr   = lane & 15;
    const int wr   = (wid >> 1) * 64;
    const int wc   = (wid & 1) * 32;

    const int srowA = wid * 32 + (lane >> 2);
    const int srowW = wid * 16 + (lane >> 2);
    const int sk8   = (lane & 3) * 8;
    const unsigned short* gA = A + (size_t)(m0 + srowA) * 1024 + sk8;
    const unsigned short* gW = W + (size_t)(n0 + srowW) * 1024 + sk8;
    unsigned short* lA = &Al[wid * 1024];
    unsigned short* lW = &Bl[wid * 512];

    f32x4 acc[4][2];
#pragma unroll
    for (int i = 0; i < 4; i++)
#pragma unroll
        for (int j = 0; j < 2; j++) acc[i][j] = (f32x4){0.f, 0.f, 0.f, 0.f};

    for (int ks = 0; ks < 1024; ks += 32) {
        __syncthreads();
        gld_lds16(gA + ks,              lA);
        gld_lds16(gA + ks + 16 * 1024,  lA + 512);
        gld_lds16(gW + ks,              lW);
        __syncthreads();

        s16x8 af[4], bf[2];
#pragma unroll
        for (int mt = 0; mt < 4; mt++)
            af[mt] = *(const s16x8*)&Al[(wr + mt * 16 + lr) * 32 + quad * 8];
#pragma unroll
        for (int nt = 0; nt < 2; nt++)
            bf[nt] = *(const s16x8*)&Bl[(wc + nt * 16 + lr) * 32 + quad * 8];
#pragma unroll
        for (int mt = 0; mt < 4; mt++)
#pragma unroll
            for (int nt = 0; nt < 2; nt++)
                acc[mt][nt] = MFMA_BF16(af[mt], bf[nt], acc[mt][nt]);
    }

#pragma unroll
    for (int mt = 0; mt < 4; mt++)
#pragma unroll
        for (int nt = 0; nt < 2; nt++) {
            int   col  = n0 + wc + nt * 16 + lr;
            float bcol = bias[col];
            int   rbase = m0 + wr + mt * 16 + quad * 4;
#pragma unroll
            for (int r = 0; r < 4; r++)
                C[(size_t)(rbase + r) * 1024 + col] = acc[mt][nt][r] + bcol;
        }
}

// ---------------------------------------------------------------------------
// Flash attention v8 (frozen from R7): 32x32 quarter-split, XCD swizzle,
// conflict-free ST=76, chain-free exp2 softmax. 73 µs, FETCH 12.3 MB.
// ---------------------------------------------------------------------------
__global__ __launch_bounds__(256)
void flash_attn(const unsigned short* __restrict__ Q,
                const unsigned short* __restrict__ K,
                const unsigned short* __restrict__ Vt,
                const float* __restrict__ maskf,
                unsigned short* __restrict__ O)
{
    constexpr int   ST  = 76;
    constexpr float EPS = 9.31322575e-10f;  // 2^-30
    __shared__ __align__(16) unsigned short Kl[64 * ST]; // [key][d]
    __shared__ __align__(16) unsigned short Vl[64 * ST]; // [d][key]
    __shared__ __align__(16) unsigned short Pl[64 * ST]; // [q][key]
    __shared__ float lsq[4][32];

    const int id    = blockIdx.x;
    const int xcd   = id & 7;
    const int local = id >> 3;
    const int pair  = xcd * 4 + (local >> 5);
    const int b     = pair >> 4;
    const int h     = pair & 15;
    const int q0    = (local & 31) * 64;

    const int tid  = threadIdx.x;
    const int lane = tid & 63;
    const int wid  = tid >> 6;
    const int l31  = lane & 31;
    const int hl   = lane >> 5;
    const int qh   = wid & 1;
    const int kh   = wid >> 1;

    const unsigned short* qg =
        Q + (size_t)(b * 2048 + q0 + qh * 32 + l31) * 1024 + h * 64 + hl * 8;
    s16x8 qf[4];
#pragma unroll
    for (int db = 0; db < 4; db++) qf[db] = *(const s16x8*)(qg + db * 16);

    const float  mq  = maskf[b * 2048 + q0 + qh * 32 + l31];
    const float* mkp = maskf + b * 2048;

    const int lk = (tid >> 3) * ST + (tid & 7) * 8;
    const unsigned short* gK = K  + (size_t)(b * 2048 + (tid >> 3)) * 1024 + h * 64 + (tid & 7) * 8;
    const unsigned short* gV = Vt + (size_t)(b * 1024 + h * 64 + (tid >> 3)) * 2048 + (tid & 7) * 8;

    float  lsum = 0.f;
    f32x16 accO = (f32x16){0.f,0.f,0.f,0.f,0.f,0.f,0.f,0.f,
                           0.f,0.f,0.f,0.f,0.f,0.f,0.f,0.f};

    for (int kt = 0; kt < 2048; kt += 64) {
        __syncthreads();
        *(u16x8*)&Kl[lk]           = *(const u16x8*)(gK + (size_t)kt * 1024);
        *(u16x8*)&Kl[lk + 32 * ST] = *(const u16x8*)(gK + (size_t)(kt + 32) * 1024);
        *(u16x8*)&Vl[lk]           = *(const u16x8*)(gV + kt);
        *(u16x8*)&Vl[lk + 32 * ST] = *(const u16x8*)(gV + kt + (size_t)32 * 2048);
        __syncthreads();

        f32x16 st = (f32x16){0.f,0.f,0.f,0.f,0.f,0.f,0.f,0.f,
                             0.f,0.f,0.f,0.f,0.f,0.f,0.f,0.f};
#pragma unroll
        for (int db = 0; db < 4; db++) {
            s16x8 kf = *(const s16x8*)&Kl[(kh * 32 + l31) * ST + db * 16 + hl * 8];
            st = MFMA32(kf, qf[db], st);
        }
#pragma unroll
        for (int rq = 0; rq < 4; rq++) {
            int   kb = 4 * hl + 8 * rq;
            f32x4 m4 = *(const f32x4*)&mkp[kt + kh * 32 + kb];
            unsigned u[4];
#pragma unroll
            for (int r = 0; r < 4; r++) {
                float e = __builtin_amdgcn_exp2f(st[rq * 4 + r]);
                float p = e * (m4[r] * mq) + EPS;
                lsum += p;
                u[r] = __builtin_bit_cast(unsigned, p) + 0x8000u;
            }
            uint2 w;
            w.x = __builtin_amdgcn_perm(u[1], u[0], 0x07060302u);
            w.y = __builtin_amdgcn_perm(u[3], u[2], 0x07060302u);
            *(uint2*)&Pl[(qh * 32 + l31) * ST + kh * 32 + kb] = w;
        }
        __syncthreads();

#pragma unroll
        for (int ks = 0; ks < 4; ks++) {
            s16x8 pf = *(const s16x8*)&Pl[(qh * 32 + l31) * ST + ks * 16 + hl * 8];
            s16x8 vf = *(const s16x8*)&Vl[(kh * 32 + l31) * ST + ks * 16 + hl * 8];
            accO = MFMA32(pf, vf, accO);
        }
    }

    lsum += __shfl_xor(lsum, 32, 64);
    lsq[wid][l31] = lsum;
    __syncthreads();

#pragma unroll
    for (int rq = 0; rq < 4; rq++) {
        int   qr = 4 * hl + 8 * rq;
        f32x4 lA = *(const f32x4*)&lsq[qh][qr];
        f32x4 lB = *(const f32x4*)&lsq[qh + 2][qr];
#pragma unroll
        for (int r = 0; r < 4; r++) {
            float val = accO[rq * 4 + r] * __builtin_amdgcn_rcpf(lA[r] + lB[r]);
            O[(size_t)(b * 2048 + q0 + qh * 32 + qr + r) * 1024 + h * 64 +
              kh * 32 + l31] = f2b(val);
        }
    }
}

// ---------------------------------------------------------------------------
extern "C" void kernel_launch(void* const* d_in, const int* in_sizes, int n_in,
                              void* d_out, int out_size, void* d_ws, size_t ws_size,
                              hipStream_t stream)
{
    const float* query = (const float*)d_in[0];
    const float* key_  = (const float*)d_in[1];
    const float* value = (const float*)d_in[2];
    const int*   mask  = (const int*)d_in[3];
    const float* Wq    = (const float*)d_in[4];
    const float* bq    = (const float*)d_in[5];
    const float* Wk    = (const float*)d_in[6];
    const float* bk    = (const float*)d_in[7];
    const float* Wv    = (const float*)d_in[8];
    const float* bv    = (const float*)d_in[9];
    const float* Wo    = (const float*)d_in[10];
    const float* bo    = (const float*)d_in[11];
    float* out = (float*)d_out;

    unsigned short* cvt = (unsigned short*)d_ws;
    unsigned short* Aq  = cvt;
    unsigned short* Ak  = cvt + M4;
    unsigned short* Av  = cvt + 2 * M4;
    unsigned short* Wqb = cvt + 3 * M4;
    unsigned short* Wkb = Wqb + M1;
    unsigned short* Wvb = Wkb + M1;
    unsigned short* Wob = Wvb + M1;
    unsigned short* Qb  = Wob + M1;
    unsigned short* Kb  = Qb + M4;
    unsigned short* Vt  = Kb + M4;
    unsigned short* Ab  = Vt + M4;
    float*          mkf = (float*)(Ab + M4);

    CvtArgs ca;
    ca.src[0] = query; ca.src[1] = key_; ca.src[2] = value;
    ca.src[3] = Wq; ca.src[4] = Wk; ca.src[5] = Wv; ca.src[6] = Wo;
    ca.dst = cvt; ca.mask = mask; ca.maskf = mkf;
    cvt_bf16<<<dim3(8193), 256, 0, stream>>>(ca);

    GArgs ga;
    ga.A[0] = Aq;  ga.A[1] = Ak;  ga.A[2] = Av;
    ga.W[0] = Wqb; ga.W[1] = Wkb; ga.W[2] = Wvb;
    ga.bias[0] = bq; ga.bias[1] = bk; ga.bias[2] = bv;
    ga.C[0] = Qb; ga.C[1] = Kb; ga.C[2] = Vt;
    proj_gemm<<<dim3(768), 256, 0, stream>>>(ga);

    flash_attn<<<dim3(1024), 256, 0, stream>>>(Qb, Kb, Vt, mkf, Ab);
    out_gemm<<<dim3(512), 256, 0, stream>>>(Ab, Wob, bo, out);
}